// Round 7
// baseline (414.303 us; speedup 1.0000x reference)
//
#include <hip/hip_runtime.h>
#include <hip/hip_bf16.h>
#include <stdint.h>

#define DIMD 512
#define LNEPS 1e-5f

typedef __attribute__((ext_vector_type(8))) short short8;
typedef __attribute__((ext_vector_type(4))) float f32x4;

static __device__ __forceinline__ unsigned short f2bf(float x) {
  unsigned u = __builtin_bit_cast(unsigned, x);
  unsigned r = (u + 0x7FFFu + ((u >> 16) & 1u)) >> 16;
  return (unsigned short)r;
}
static __device__ __forceinline__ float bf2f(unsigned short h) {
  return __builtin_bit_cast(float, ((unsigned)h) << 16);
}

// ---------------- degree / CSR build ----------------

__global__ __launch_bounds__(256) void deg_kernel(const int* __restrict__ src, const int* __restrict__ dst,
                                                  int* __restrict__ outdeg, int* __restrict__ indeg, int e) {
  int i = blockIdx.x * 256 + threadIdx.x;
  if (i < e) {
    atomicAdd(&outdeg[src[i]], 1);
    atomicAdd(&indeg[dst[i]], 1);
  }
}

__global__ __launch_bounds__(256) void norm_kernel(const int* __restrict__ outdeg, const int* __restrict__ indeg,
                                                   float* __restrict__ ns, float* __restrict__ nd, int n) {
  int i = blockIdx.x * 256 + threadIdx.x;
  if (i < n) {
    ns[i] = rsqrtf((float)max(outdeg[i], 1));
    nd[i] = rsqrtf((float)max(indeg[i], 1));
  }
}

// wave-shfl based block scan, single block of 1024 threads
__global__ __launch_bounds__(1024) void scan_kernel(const int* __restrict__ cnt, int* __restrict__ rp,
                                                    int* __restrict__ cursor, int n) {
  __shared__ int wsum[16];
  __shared__ int carry_s;
  const int tid = threadIdx.x;
  const int lane = tid & 63;
  const int wid = tid >> 6;
  if (tid == 0) carry_s = 0;
  __syncthreads();
  for (int base = 0; base < n; base += 1024) {
    const int i = base + tid;
    const int x = (i < n) ? cnt[i] : 0;
    int incl = x;
    #pragma unroll
    for (int o = 1; o < 64; o <<= 1) {
      int t = __shfl_up(incl, o);
      if (lane >= o) incl += t;
    }
    if (lane == 63) wsum[wid] = incl;
    __syncthreads();
    if (wid == 0) {
      int v = (lane < 16) ? wsum[lane] : 0;
      #pragma unroll
      for (int o = 1; o < 16; o <<= 1) {
        int t = __shfl_up(v, o);
        if (lane >= o) v += t;
      }
      if (lane < 16) wsum[lane] = v;
    }
    __syncthreads();
    const int carry = carry_s;
    const int woff = wid ? wsum[wid - 1] : 0;
    if (i < n) {
      const int excl = carry + woff + incl - x;
      rp[i] = excl;
      cursor[i] = excl;
    }
    __syncthreads();
    if (tid == 0) carry_s = carry + wsum[15];
    __syncthreads();
  }
  if (tid == 0) rp[n] = carry_s;
}

__global__ __launch_bounds__(256) void fill_kernel(const int* __restrict__ src, const int* __restrict__ dst,
                                                   int* __restrict__ cursor, int* __restrict__ eidx, int e) {
  int i = blockIdx.x * 256 + threadIdx.x;
  if (i < e) {
    int p = atomicAdd(&cursor[dst[i]], 1);
    eidx[p] = src[i];
  }
}

// ---------------- W split (hi only) + transpose ----------------

__global__ __launch_bounds__(256) void wsplit_kernel(const float* __restrict__ W,
                                                     unsigned short* __restrict__ WhiT, int total) {
  int idx = blockIdx.x * 256 + threadIdx.x;
  if (idx >= total) return;
  int l = idx >> 18;
  int rem = idx & 262143;
  int k = rem >> 9;
  int nn = rem & 511;
  float w = W[idx];
  size_t o = ((size_t)l << 18) + ((size_t)nn << 9) + (size_t)k;
  WhiT[o] = f2bf(w);
}

// ---------------- LayerNorm + ns scaling + bf16 split (fp32 input; layer 0) ----------------

__global__ __launch_bounds__(128) void ln_split_kernel(const float* __restrict__ h,
                                                       unsigned short* __restrict__ Ahi,
                                                       unsigned short* __restrict__ Alo,
                                                       const float* __restrict__ g, const float* __restrict__ bb,
                                                       const float* __restrict__ ns) {
  int v = blockIdx.x;
  int tid = threadIdx.x;
  const float4* hv = (const float4*)(h + (size_t)v * DIMD);
  float4 x = hv[tid];
  float s = x.x + x.y + x.z + x.w;
  #pragma unroll
  for (int m = 32; m; m >>= 1) s += __shfl_xor(s, m);
  __shared__ float red[2];
  __shared__ float red2[2];
  int wid = tid >> 6;
  if ((tid & 63) == 0) red[wid] = s;
  __syncthreads();
  float mu = (red[0] + red[1]) * (1.0f / 512.0f);
  float4 c = make_float4(x.x - mu, x.y - mu, x.z - mu, x.w - mu);
  float s2 = c.x * c.x + c.y * c.y + c.z * c.z + c.w * c.w;
  #pragma unroll
  for (int m = 32; m; m >>= 1) s2 += __shfl_xor(s2, m);
  if ((tid & 63) == 0) red2[wid] = s2;
  __syncthreads();
  float var = (red2[0] + red2[1]) * (1.0f / 512.0f);
  float rstd = rsqrtf(var + LNEPS);
  float scale = ns[v];
  float4 g4 = ((const float4*)g)[tid];
  float4 b4 = ((const float4*)bb)[tid];
  float4 o;
  o.x = (c.x * rstd * g4.x + b4.x) * scale;
  o.y = (c.y * rstd * g4.y + b4.y) * scale;
  o.z = (c.z * rstd * g4.z + b4.z) * scale;
  o.w = (c.w * rstd * g4.w + b4.w) * scale;
  ushort4 h4, l4;
  h4.x = f2bf(o.x); l4.x = f2bf(o.x - bf2f(h4.x));
  h4.y = f2bf(o.y); l4.y = f2bf(o.y - bf2f(h4.y));
  h4.z = f2bf(o.z); l4.z = f2bf(o.z - bf2f(h4.z));
  h4.w = f2bf(o.w); l4.w = f2bf(o.w - bf2f(h4.w));
  ((ushort4*)(Ahi + (size_t)v * DIMD))[tid] = h4;
  ((ushort4*)(Alo + (size_t)v * DIMD))[tid] = l4;
}

// ---------------- LayerNorm + ns scaling + bf16 split (bf16 input; mid layers) ----------------

__global__ __launch_bounds__(128) void ln_split_bf16(const unsigned short* __restrict__ G,
                                                     unsigned short* __restrict__ Ahi,
                                                     unsigned short* __restrict__ Alo,
                                                     const float* __restrict__ g, const float* __restrict__ bb,
                                                     const float* __restrict__ ns) {
  int v = blockIdx.x;
  int tid = threadIdx.x;
  ushort4 xr = ((const ushort4*)(G + (size_t)v * DIMD))[tid];
  float4 x = make_float4(bf2f(xr.x), bf2f(xr.y), bf2f(xr.z), bf2f(xr.w));
  float s = x.x + x.y + x.z + x.w;
  #pragma unroll
  for (int m = 32; m; m >>= 1) s += __shfl_xor(s, m);
  __shared__ float red[2];
  __shared__ float red2[2];
  int wid = tid >> 6;
  if ((tid & 63) == 0) red[wid] = s;
  __syncthreads();
  float mu = (red[0] + red[1]) * (1.0f / 512.0f);
  float4 c = make_float4(x.x - mu, x.y - mu, x.z - mu, x.w - mu);
  float s2 = c.x * c.x + c.y * c.y + c.z * c.z + c.w * c.w;
  #pragma unroll
  for (int m = 32; m; m >>= 1) s2 += __shfl_xor(s2, m);
  if ((tid & 63) == 0) red2[wid] = s2;
  __syncthreads();
  float var = (red2[0] + red2[1]) * (1.0f / 512.0f);
  float rstd = rsqrtf(var + LNEPS);
  float scale = ns[v];
  float4 g4 = ((const float4*)g)[tid];
  float4 b4 = ((const float4*)bb)[tid];
  float4 o;
  o.x = (c.x * rstd * g4.x + b4.x) * scale;
  o.y = (c.y * rstd * g4.y + b4.y) * scale;
  o.z = (c.z * rstd * g4.z + b4.z) * scale;
  o.w = (c.w * rstd * g4.w + b4.w) * scale;
  ushort4 h4, l4;
  h4.x = f2bf(o.x); l4.x = f2bf(o.x - bf2f(h4.x));
  h4.y = f2bf(o.y); l4.y = f2bf(o.y - bf2f(h4.y));
  h4.z = f2bf(o.z); l4.z = f2bf(o.z - bf2f(h4.z));
  h4.w = f2bf(o.w); l4.w = f2bf(o.w - bf2f(h4.w));
  ((ushort4*)(Ahi + (size_t)v * DIMD))[tid] = h4;
  ((ushort4*)(Alo + (size_t)v * DIMD))[tid] = l4;
}

// ---------------- fp32 LN (fallback path) ----------------

__global__ __launch_bounds__(128) void ln_scale_kernel(const float* __restrict__ h, float* __restrict__ out,
                                                       const float* __restrict__ g, const float* __restrict__ bb,
                                                       const float* __restrict__ ns) {
  int v = blockIdx.x;
  int tid = threadIdx.x;
  const float4* hv = (const float4*)(h + (size_t)v * DIMD);
  float4 x = hv[tid];
  float s = x.x + x.y + x.z + x.w;
  #pragma unroll
  for (int m = 32; m; m >>= 1) s += __shfl_xor(s, m);
  __shared__ float red[2];
  __shared__ float red2[2];
  int wid = tid >> 6;
  if ((tid & 63) == 0) red[wid] = s;
  __syncthreads();
  float mu = (red[0] + red[1]) * (1.0f / 512.0f);
  float4 c = make_float4(x.x - mu, x.y - mu, x.z - mu, x.w - mu);
  float s2 = c.x * c.x + c.y * c.y + c.z * c.z + c.w * c.w;
  #pragma unroll
  for (int m = 32; m; m >>= 1) s2 += __shfl_xor(s2, m);
  if ((tid & 63) == 0) red2[wid] = s2;
  __syncthreads();
  float var = (red2[0] + red2[1]) * (1.0f / 512.0f);
  float rstd = rsqrtf(var + LNEPS);
  float scale = ns[v];
  float4 g4 = ((const float4*)g)[tid];
  float4 b4 = ((const float4*)bb)[tid];
  float4 o;
  o.x = (c.x * rstd * g4.x + b4.x) * scale;
  o.y = (c.y * rstd * g4.y + b4.y) * scale;
  o.z = (c.z * rstd * g4.z + b4.z) * scale;
  o.w = (c.w * rstd * g4.w + b4.w) * scale;
  ((float4*)(out + (size_t)v * DIMD))[tid] = o;
}

// ---------------- split-bf16 MFMA GEMM, 2 products (Ahi@Whi + Alo@Whi), BK=32 ----------------

__global__ __launch_bounds__(256, 4) void gemm_mfma_bf16out(const unsigned short* __restrict__ Ahi,
                                                            const unsigned short* __restrict__ Alo,
                                                            const unsigned short* __restrict__ BhiT,
                                                            unsigned short* __restrict__ C, int M) {
  __shared__ char lds[24576];
  char* sAhi = lds;            // 128 rows x 64 B
  char* sAlo = lds + 8192;
  char* sBhi = lds + 16384;
  const int tid = threadIdx.x;
  const int lane = tid & 63;
  const int w = tid >> 6;
  const int tileM = blockIdx.y * 128;
  const int tileN = blockIdx.x * 128;
  const int wm = (w >> 1) * 64;
  const int wn = (w & 1) * 64;

  f32x4 acc[4][4] = {};

  for (int k0 = 0; k0 < DIMD; k0 += 32) {
    #pragma unroll
    for (int i = 0; i < 2; ++i) {
      const int c = i * 256 + tid;                   // 16B chunk id 0..511
      const int r = c >> 2;                          // tile row 0..127
      const int q = c & 3;                           // quarter within 64B row
      const int kb = (q ^ ((r >> 1) & 3)) * 16;      // pre-swizzled k-byte
      int gra = tileM + r; gra = gra < M ? gra : M - 1;
      const size_t aoff = (size_t)gra * (DIMD * 2) + (size_t)(k0 * 2 + kb);
      const size_t boff = (size_t)(tileN + r) * (DIMD * 2) + (size_t)(k0 * 2 + kb);
      const int lbase = c * 16;                      // linear LDS dest
      __builtin_amdgcn_global_load_lds((const __attribute__((address_space(1))) unsigned int*)((const char*)Ahi + aoff),
                                       (__attribute__((address_space(3))) unsigned int*)(sAhi + lbase), 16, 0, 0);
      __builtin_amdgcn_global_load_lds((const __attribute__((address_space(1))) unsigned int*)((const char*)Alo + aoff),
                                       (__attribute__((address_space(3))) unsigned int*)(sAlo + lbase), 16, 0, 0);
      __builtin_amdgcn_global_load_lds((const __attribute__((address_space(1))) unsigned int*)((const char*)BhiT + boff),
                                       (__attribute__((address_space(3))) unsigned int*)(sBhi + lbase), 16, 0, 0);
    }
    __syncthreads();
    const int qr = lane >> 4;                        // k-quarter this lane consumes
    short8 ah[4], al[4], bh[4];
    #pragma unroll
    for (int mf = 0; mf < 4; ++mf) {
      const int r = wm + mf * 16 + (lane & 15);
      const int kb = (qr ^ ((r >> 1) & 3)) * 16;
      ah[mf] = *(const short8*)(sAhi + r * 64 + kb);
      al[mf] = *(const short8*)(sAlo + r * 64 + kb);
    }
    #pragma unroll
    for (int nf = 0; nf < 4; ++nf) {
      const int r = wn + nf * 16 + (lane & 15);
      const int kb = (qr ^ ((r >> 1) & 3)) * 16;
      bh[nf] = *(const short8*)(sBhi + r * 64 + kb);
    }
    #pragma unroll
    for (int mf = 0; mf < 4; ++mf) {
      #pragma unroll
      for (int nf = 0; nf < 4; ++nf) {
        acc[mf][nf] = __builtin_amdgcn_mfma_f32_16x16x32_bf16(ah[mf], bh[nf], acc[mf][nf], 0, 0, 0);
        acc[mf][nf] = __builtin_amdgcn_mfma_f32_16x16x32_bf16(al[mf], bh[nf], acc[mf][nf], 0, 0, 0);
      }
    }
    __syncthreads();
  }
  #pragma unroll
  for (int mf = 0; mf < 4; ++mf) {
    const int rb = tileM + wm + mf * 16 + (lane >> 4) * 4;
    #pragma unroll
    for (int nf = 0; nf < 4; ++nf) {
      const int col = tileN + wn + nf * 16 + (lane & 15);
      #pragma unroll
      for (int j = 0; j < 4; ++j) {
        const int row = rb + j;
        if (row < M) C[(size_t)row * DIMD + col] = f2bf(acc[mf][nf][j]);
      }
    }
  }
}

// ---------------- fp32 tiled GEMM (fallback) ----------------

__global__ __launch_bounds__(256) void gemm_fp32(const float* __restrict__ A, const float* __restrict__ W,
                                                 float* __restrict__ C, int M) {
  const int K = DIMD, N = DIMD;
  __shared__ float As[16][65];
  __shared__ float Bs[16][64];
  int tid = threadIdx.x;
  int tileM = blockIdx.x * 64;
  int tileN = blockIdx.y * 64;
  int tx = tid & 15, ty = tid >> 4;
  float acc[4][4] = {};
  int arow = tid >> 2;
  int acol = (tid & 3) * 4;
  int brow = tid >> 4;
  int bcol = (tid & 15) * 4;

  for (int k0 = 0; k0 < K; k0 += 16) {
    float4 a4 = make_float4(0.f, 0.f, 0.f, 0.f);
    int gr = tileM + arow;
    if (gr < M) a4 = *(const float4*)(A + (size_t)gr * K + k0 + acol);
    As[acol + 0][arow] = a4.x;
    As[acol + 1][arow] = a4.y;
    As[acol + 2][arow] = a4.z;
    As[acol + 3][arow] = a4.w;
    float4 b4 = *(const float4*)(W + (size_t)(k0 + brow) * N + tileN + bcol);
    *(float4*)(&Bs[brow][bcol]) = b4;
    __syncthreads();
    #pragma unroll
    for (int kk = 0; kk < 16; ++kk) {
      float a[4];
      #pragma unroll
      for (int i = 0; i < 4; ++i) a[i] = As[kk][ty * 4 + i];
      float4 b = *(const float4*)(&Bs[kk][tx * 4]);
      #pragma unroll
      for (int i = 0; i < 4; ++i) {
        acc[i][0] += a[i] * b.x;
        acc[i][1] += a[i] * b.y;
        acc[i][2] += a[i] * b.z;
        acc[i][3] += a[i] * b.w;
      }
    }
    __syncthreads();
  }
  #pragma unroll
  for (int i = 0; i < 4; ++i) {
    int gr = tileM + ty * 4 + i;
    if (gr < M) {
      float4 o = make_float4(acc[i][0], acc[i][1], acc[i][2], acc[i][3]);
      *(float4*)(C + (size_t)gr * N + tileN + tx * 4) = o;
    }
  }
}

// ---------------- XCD-bound group aggregation ----------------
// 4 dim-chunks of 128; chunk = (blockIdx%8)>>1 -> XCD slice ~5MB (mostly L2-resident).
// Wave = 4 nodes x 16 lanes; each 16-lane group accumulates its node's 128-dim chunk
// privately (16B/lane, no cross-lane reduce). Block = 16 nodes, all on one chunk.
// MODE 0: mid layer -> relu(agg*nd+b) -> bf16 G. MODE 1: final -> fp32 d_out.

template <int MODE>
__global__ __launch_bounds__(256) void agg_group(const unsigned short* __restrict__ Y,
                                                 const int* __restrict__ rp, const int* __restrict__ eidx,
                                                 const float* __restrict__ nd, const float* __restrict__ bias,
                                                 unsigned short* __restrict__ Gbf, float* __restrict__ outf,
                                                 int n) {
  const int bid = blockIdx.x;
  const int chunk = (bid & 7) >> 1;
  const int gblk = bid >> 3;
  const int w = threadIdx.x >> 6;
  const int lane = threadIdx.x & 63;
  const int grp = lane >> 4;                 // node slot in wave 0..3
  const int dl = lane & 15;                  // dim lane 0..15 (8 dims each)
  const int v = gblk * 16 + w * 4 + grp;
  const int vc = v < n ? v : n - 1;
  const int dbase = chunk * 128 + dl * 8;
  const int beg = rp[vc], end = rp[vc + 1];
  float acc[8] = {0.f, 0.f, 0.f, 0.f, 0.f, 0.f, 0.f, 0.f};
  int j = beg;
  for (; j + 3 < end; j += 4) {
    const int e0 = eidx[j], e1 = eidx[j + 1], e2 = eidx[j + 2], e3 = eidx[j + 3];
    const short8 m0 = *(const short8*)(Y + (size_t)e0 * DIMD + dbase);
    const short8 m1 = *(const short8*)(Y + (size_t)e1 * DIMD + dbase);
    const short8 m2 = *(const short8*)(Y + (size_t)e2 * DIMD + dbase);
    const short8 m3 = *(const short8*)(Y + (size_t)e3 * DIMD + dbase);
    #pragma unroll
    for (int k = 0; k < 8; ++k)
      acc[k] += (bf2f((unsigned short)m0[k]) + bf2f((unsigned short)m1[k])) +
                (bf2f((unsigned short)m2[k]) + bf2f((unsigned short)m3[k]));
  }
  for (; j < end; ++j) {
    const short8 m0 = *(const short8*)(Y + (size_t)eidx[j] * DIMD + dbase);
    #pragma unroll
    for (int k = 0; k < 8; ++k) acc[k] += bf2f((unsigned short)m0[k]);
  }
  if (v >= n) return;
  const float f = nd[v];
  const float4 b0 = *(const float4*)(bias + dbase);
  const float4 b1 = *(const float4*)(bias + dbase + 4);
  float o8[8];
  o8[0] = acc[0] * f + b0.x; o8[1] = acc[1] * f + b0.y;
  o8[2] = acc[2] * f + b0.z; o8[3] = acc[3] * f + b0.w;
  o8[4] = acc[4] * f + b1.x; o8[5] = acc[5] * f + b1.y;
  o8[6] = acc[6] * f + b1.z; o8[7] = acc[7] * f + b1.w;
  if (MODE == 0) {
    short8 pk;
    #pragma unroll
    for (int k = 0; k < 8; ++k) pk[k] = (short)f2bf(fmaxf(o8[k], 0.f));
    *(short8*)(Gbf + (size_t)v * DIMD + dbase) = pk;
  } else {
    *(float4*)(outf + (size_t)v * DIMD + dbase) = make_float4(o8[0], o8[1], o8[2], o8[3]);
    *(float4*)(outf + (size_t)v * DIMD + dbase + 4) = make_float4(o8[4], o8[5], o8[6], o8[7]);
  }
}

// ---------------- fp32 aggregation (fallback) ----------------

__global__ __launch_bounds__(128) void agg_kernel(const float* __restrict__ Y, const int* __restrict__ rp,
                                                  const int* __restrict__ eidx, const float* __restrict__ nd,
                                                  const float* __restrict__ bias, float* __restrict__ out,
                                                  int do_relu) {
  int v = blockIdx.x;
  int tid = threadIdx.x;
  int beg = rp[v], end = rp[v + 1];
  float4 acc = make_float4(0.f, 0.f, 0.f, 0.f);
  for (int j = beg; j < end; ++j) {
    int s = eidx[j];
    float4 m = ((const float4*)(Y + (size_t)s * DIMD))[tid];
    acc.x += m.x; acc.y += m.y; acc.z += m.z; acc.w += m.w;
  }
  float f = nd[v];
  float4 b4 = ((const float4*)bias)[tid];
  float4 o = make_float4(acc.x * f + b4.x, acc.y * f + b4.y, acc.z * f + b4.z, acc.w * f + b4.w);
  if (do_relu) {
    o.x = fmaxf(o.x, 0.f); o.y = fmaxf(o.y, 0.f); o.z = fmaxf(o.z, 0.f); o.w = fmaxf(o.w, 0.f);
  }
  ((float4*)(out + (size_t)v * DIMD))[tid] = o;
}

// ---------------- launch ----------------

extern "C" void kernel_launch(void* const* d_in, const int* in_sizes, int n_in,
                              void* d_out, int out_size, void* d_ws, size_t ws_size,
                              hipStream_t stream) {
  const float* feats = (const float*)d_in[0];
  const int* src = (const int*)d_in[1];
  const int* dst = (const int*)d_in[2];
  const float* ln_g = (const float*)d_in[3];
  const float* ln_b = (const float*)d_in[4];
  const float* W = (const float*)d_in[5];
  const float* bias = (const float*)d_in[6];
  const int n = in_sizes[0] / DIMD;
  const int e = in_sizes[1];
  const int L = in_sizes[3] / DIMD;  // 3

  char* ws = (char*)d_ws;
  size_t off = 0;
  auto alloc = [&](size_t bytes) {
    void* p = ws + off;
    off = (off + bytes + 255) & ~(size_t)255;
    return p;
  };

  const size_t misc_bytes = ((size_t)n * 4 + 256) * 6 + ((size_t)(n + 1) * 4 + 256) + ((size_t)e * 4 + 256);
  const size_t fast_need = 2 * ((size_t)(n + 128) * DIMD * 2 + 256)   // Ahi/Alo
                         + ((size_t)n * DIMD * 2 + 256)               // Ybf
                         + ((size_t)n * DIMD * 2 + 256)               // Gbf
                         + ((size_t)L * DIMD * DIMD * 2 + 256)        // WhiT
                         + misc_bytes;

  const bool fast = ws_size >= fast_need;

  float* O = (float*)d_out;
  int eb = (e + 255) / 256;
  int nb = (n + 255) / 256;

  if (fast) {
    unsigned short* Ahi = (unsigned short*)alloc((size_t)(n + 128) * DIMD * 2);
    unsigned short* Alo = (unsigned short*)alloc((size_t)(n + 128) * DIMD * 2);
    unsigned short* Ybf = (unsigned short*)alloc((size_t)n * DIMD * 2);
    unsigned short* Gbf = (unsigned short*)alloc((size_t)n * DIMD * 2);
    unsigned short* WhiT = (unsigned short*)alloc((size_t)L * DIMD * DIMD * 2);
    float* ns = (float*)alloc((size_t)n * 4);
    float* nd = (float*)alloc((size_t)n * 4);
    int* outdeg = (int*)alloc((size_t)n * 4);
    int* indeg = (int*)alloc((size_t)n * 4);
    int* rp = (int*)alloc((size_t)(n + 1) * 4);
    int* cursor = (int*)alloc((size_t)n * 4);
    int* eidx = (int*)alloc((size_t)e * 4);

    hipMemsetAsync(outdeg, 0, (size_t)n * 4, stream);
    hipMemsetAsync(indeg, 0, (size_t)n * 4, stream);

    int wtot = L * DIMD * DIMD;
    wsplit_kernel<<<(wtot + 255) / 256, 256, 0, stream>>>(W, WhiT, wtot);
    deg_kernel<<<eb, 256, 0, stream>>>(src, dst, outdeg, indeg, e);
    norm_kernel<<<nb, 256, 0, stream>>>(outdeg, indeg, ns, nd, n);
    scan_kernel<<<1, 1024, 0, stream>>>(indeg, rp, cursor, n);
    fill_kernel<<<eb, 256, 0, stream>>>(src, dst, cursor, eidx, e);

    dim3 ggrid(DIMD / 128, (n + 127) / 128);  // N-tiles fastest: A-slice L2/L3 reuse
    const int agrid = ((n + 15) / 16) * 8;    // (node-block, slot) ; slot -> XCD -> chunk
    ln_split_kernel<<<n, 128, 0, stream>>>(feats, Ahi, Alo, ln_g, ln_b, ns);
    for (int l = 0; l < L; ++l) {
      gemm_mfma_bf16out<<<ggrid, 256, 0, stream>>>(Ahi, Alo, WhiT + (size_t)l * DIMD * DIMD, Ybf, n);
      if (l < L - 1) {
        agg_group<0><<<agrid, 256, 0, stream>>>(Ybf, rp, eidx, nd, bias + (size_t)l * DIMD, Gbf, nullptr, n);
        ln_split_bf16<<<n, 128, 0, stream>>>(Gbf, Ahi, Alo,
                                             ln_g + (size_t)(l + 1) * DIMD, ln_b + (size_t)(l + 1) * DIMD, ns);
      } else {
        agg_group<1><<<agrid, 256, 0, stream>>>(Ybf, rp, eidx, nd, bias + (size_t)l * DIMD, nullptr, O, n);
      }
    }
  } else {
    // fallback: fp32 pipeline
    float* X = (float*)alloc((size_t)n * DIMD * 4);
    float* ns = (float*)alloc((size_t)n * 4);
    float* nd = (float*)alloc((size_t)n * 4);
    int* outdeg = (int*)alloc((size_t)n * 4);
    int* indeg = (int*)alloc((size_t)n * 4);
    int* rp = (int*)alloc((size_t)(n + 1) * 4);
    int* cursor = (int*)alloc((size_t)n * 4);
    int* eidx = (int*)alloc((size_t)e * 4);

    hipMemsetAsync(outdeg, 0, (size_t)n * 4, stream);
    hipMemsetAsync(indeg, 0, (size_t)n * 4, stream);

    deg_kernel<<<eb, 256, 0, stream>>>(src, dst, outdeg, indeg, e);
    norm_kernel<<<nb, 256, 0, stream>>>(outdeg, indeg, ns, nd, n);
    scan_kernel<<<1, 1024, 0, stream>>>(indeg, rp, cursor, n);
    fill_kernel<<<eb, 256, 0, stream>>>(src, dst, cursor, eidx, e);

    const float* cur = feats;
    dim3 ggrid((n + 63) / 64, DIMD / 64);
    for (int l = 0; l < L; ++l) {
      int s = 3 * l;
      float* ln_out = (s & 1) ? X : O;
      float* mm_out = ((s + 1) & 1) ? X : O;
      float* ag_out = ((s + 2) & 1) ? X : O;
      ln_scale_kernel<<<n, 128, 0, stream>>>(cur, ln_out, ln_g + (size_t)l * DIMD, ln_b + (size_t)l * DIMD, ns);
      gemm_fp32<<<ggrid, 256, 0, stream>>>(ln_out, W + (size_t)l * DIMD * DIMD, mm_out, n);
      agg_kernel<<<n, 128, 0, stream>>>(mm_out, rp, eidx, nd, bias + (size_t)l * DIMD, ag_out, (l < L - 1) ? 1 : 0);
      cur = ag_out;
    }
  }
}

// Round 8
// 355.015 us; speedup vs baseline: 1.1670x; 1.1670x over previous
//
#include <hip/hip_runtime.h>
#include <hip/hip_bf16.h>
#include <stdint.h>

#define DIMD 512
#define LNEPS 1e-5f

typedef __attribute__((ext_vector_type(8))) short short8;
typedef __attribute__((ext_vector_type(4))) float f32x4;

static __device__ __forceinline__ unsigned short f2bf(float x) {
  unsigned u = __builtin_bit_cast(unsigned, x);
  unsigned r = (u + 0x7FFFu + ((u >> 16) & 1u)) >> 16;
  return (unsigned short)r;
}
static __device__ __forceinline__ float bf2f(unsigned short h) {
  return __builtin_bit_cast(float, ((unsigned)h) << 16);
}

// ---------------- degree / CSR build ----------------

__global__ __launch_bounds__(256) void deg_kernel(const int* __restrict__ src, const int* __restrict__ dst,
                                                  int* __restrict__ outdeg, int* __restrict__ indeg, int e) {
  int i = blockIdx.x * 256 + threadIdx.x;
  if (i < e) {
    atomicAdd(&outdeg[src[i]], 1);
    atomicAdd(&indeg[dst[i]], 1);
  }
}

__global__ __launch_bounds__(256) void norm_kernel(const int* __restrict__ outdeg, const int* __restrict__ indeg,
                                                   float* __restrict__ ns, float* __restrict__ nd, int n) {
  int i = blockIdx.x * 256 + threadIdx.x;
  if (i < n) {
    ns[i] = rsqrtf((float)max(outdeg[i], 1));
    nd[i] = rsqrtf((float)max(indeg[i], 1));
  }
}

// wave-shfl based block scan, single block of 1024 threads
__global__ __launch_bounds__(1024) void scan_kernel(const int* __restrict__ cnt, int* __restrict__ rp,
                                                    int* __restrict__ cursor, int n) {
  __shared__ int wsum[16];
  __shared__ int carry_s;
  const int tid = threadIdx.x;
  const int lane = tid & 63;
  const int wid = tid >> 6;
  if (tid == 0) carry_s = 0;
  __syncthreads();
  for (int base = 0; base < n; base += 1024) {
    const int i = base + tid;
    const int x = (i < n) ? cnt[i] : 0;
    int incl = x;
    #pragma unroll
    for (int o = 1; o < 64; o <<= 1) {
      int t = __shfl_up(incl, o);
      if (lane >= o) incl += t;
    }
    if (lane == 63) wsum[wid] = incl;
    __syncthreads();
    if (wid == 0) {
      int v = (lane < 16) ? wsum[lane] : 0;
      #pragma unroll
      for (int o = 1; o < 16; o <<= 1) {
        int t = __shfl_up(v, o);
        if (lane >= o) v += t;
      }
      if (lane < 16) wsum[lane] = v;
    }
    __syncthreads();
    const int carry = carry_s;
    const int woff = wid ? wsum[wid - 1] : 0;
    if (i < n) {
      const int excl = carry + woff + incl - x;
      rp[i] = excl;
      cursor[i] = excl;
    }
    __syncthreads();
    if (tid == 0) carry_s = carry + wsum[15];
    __syncthreads();
  }
  if (tid == 0) rp[n] = carry_s;
}

__global__ __launch_bounds__(256) void fill_kernel(const int* __restrict__ src, const int* __restrict__ dst,
                                                   int* __restrict__ cursor, int* __restrict__ eidx, int e) {
  int i = blockIdx.x * 256 + threadIdx.x;
  if (i < e) {
    int p = atomicAdd(&cursor[dst[i]], 1);
    eidx[p] = src[i];
  }
}

// ---------------- W split (hi only) + transpose ----------------

__global__ __launch_bounds__(256) void wsplit_kernel(const float* __restrict__ W,
                                                     unsigned short* __restrict__ WhiT, int total) {
  int idx = blockIdx.x * 256 + threadIdx.x;
  if (idx >= total) return;
  int l = idx >> 18;
  int rem = idx & 262143;
  int k = rem >> 9;
  int nn = rem & 511;
  float w = W[idx];
  size_t o = ((size_t)l << 18) + ((size_t)nn << 9) + (size_t)k;
  WhiT[o] = f2bf(w);
}

// ---------------- layer-0 LayerNorm + ns scaling + bf16 split ----------------

__global__ __launch_bounds__(128) void ln_split_kernel(const float* __restrict__ h,
                                                       unsigned short* __restrict__ Ahi,
                                                       unsigned short* __restrict__ Alo,
                                                       const float* __restrict__ g, const float* __restrict__ bb,
                                                       const float* __restrict__ ns) {
  int v = blockIdx.x;
  int tid = threadIdx.x;
  const float4* hv = (const float4*)(h + (size_t)v * DIMD);
  float4 x = hv[tid];
  float s = x.x + x.y + x.z + x.w;
  #pragma unroll
  for (int m = 32; m; m >>= 1) s += __shfl_xor(s, m);
  __shared__ float red[2];
  __shared__ float red2[2];
  int wid = tid >> 6;
  if ((tid & 63) == 0) red[wid] = s;
  __syncthreads();
  float mu = (red[0] + red[1]) * (1.0f / 512.0f);
  float4 c = make_float4(x.x - mu, x.y - mu, x.z - mu, x.w - mu);
  float s2 = c.x * c.x + c.y * c.y + c.z * c.z + c.w * c.w;
  #pragma unroll
  for (int m = 32; m; m >>= 1) s2 += __shfl_xor(s2, m);
  if ((tid & 63) == 0) red2[wid] = s2;
  __syncthreads();
  float var = (red2[0] + red2[1]) * (1.0f / 512.0f);
  float rstd = rsqrtf(var + LNEPS);
  float scale = ns[v];
  float4 g4 = ((const float4*)g)[tid];
  float4 b4 = ((const float4*)bb)[tid];
  float4 o;
  o.x = (c.x * rstd * g4.x + b4.x) * scale;
  o.y = (c.y * rstd * g4.y + b4.y) * scale;
  o.z = (c.z * rstd * g4.z + b4.z) * scale;
  o.w = (c.w * rstd * g4.w + b4.w) * scale;
  ushort4 h4, l4;
  h4.x = f2bf(o.x); l4.x = f2bf(o.x - bf2f(h4.x));
  h4.y = f2bf(o.y); l4.y = f2bf(o.y - bf2f(h4.y));
  h4.z = f2bf(o.z); l4.z = f2bf(o.z - bf2f(h4.z));
  h4.w = f2bf(o.w); l4.w = f2bf(o.w - bf2f(h4.w));
  ((ushort4*)(Ahi + (size_t)v * DIMD))[tid] = h4;
  ((ushort4*)(Alo + (size_t)v * DIMD))[tid] = l4;
}

// ---------------- fp32 LN (fallback path) ----------------

__global__ __launch_bounds__(128) void ln_scale_kernel(const float* __restrict__ h, float* __restrict__ out,
                                                       const float* __restrict__ g, const float* __restrict__ bb,
                                                       const float* __restrict__ ns) {
  int v = blockIdx.x;
  int tid = threadIdx.x;
  const float4* hv = (const float4*)(h + (size_t)v * DIMD);
  float4 x = hv[tid];
  float s = x.x + x.y + x.z + x.w;
  #pragma unroll
  for (int m = 32; m; m >>= 1) s += __shfl_xor(s, m);
  __shared__ float red[2];
  __shared__ float red2[2];
  int wid = tid >> 6;
  if ((tid & 63) == 0) red[wid] = s;
  __syncthreads();
  float mu = (red[0] + red[1]) * (1.0f / 512.0f);
  float4 c = make_float4(x.x - mu, x.y - mu, x.z - mu, x.w - mu);
  float s2 = c.x * c.x + c.y * c.y + c.z * c.z + c.w * c.w;
  #pragma unroll
  for (int m = 32; m; m >>= 1) s2 += __shfl_xor(s2, m);
  if ((tid & 63) == 0) red2[wid] = s2;
  __syncthreads();
  float var = (red2[0] + red2[1]) * (1.0f / 512.0f);
  float rstd = rsqrtf(var + LNEPS);
  float scale = ns[v];
  float4 g4 = ((const float4*)g)[tid];
  float4 b4 = ((const float4*)bb)[tid];
  float4 o;
  o.x = (c.x * rstd * g4.x + b4.x) * scale;
  o.y = (c.y * rstd * g4.y + b4.y) * scale;
  o.z = (c.z * rstd * g4.z + b4.z) * scale;
  o.w = (c.w * rstd * g4.w + b4.w) * scale;
  ((float4*)(out + (size_t)v * DIMD))[tid] = o;
}

// ---------------- split-bf16 MFMA GEMM, 2 products (Ahi@Whi + Alo@Whi), BK=32 ----------------
// grid = (N/128, ceil(M/128)): N-tiles fastest so sibling blocks reuse the A-slice via L2/L3

__global__ __launch_bounds__(256, 4) void gemm_mfma_bf16out(const unsigned short* __restrict__ Ahi,
                                                            const unsigned short* __restrict__ Alo,
                                                            const unsigned short* __restrict__ BhiT,
                                                            unsigned short* __restrict__ C, int M) {
  __shared__ char lds[24576];
  char* sAhi = lds;            // 128 rows x 64 B
  char* sAlo = lds + 8192;
  char* sBhi = lds + 16384;
  const int tid = threadIdx.x;
  const int lane = tid & 63;
  const int w = tid >> 6;
  const int tileM = blockIdx.y * 128;
  const int tileN = blockIdx.x * 128;
  const int wm = (w >> 1) * 64;
  const int wn = (w & 1) * 64;

  f32x4 acc[4][4] = {};

  for (int k0 = 0; k0 < DIMD; k0 += 32) {
    #pragma unroll
    for (int i = 0; i < 2; ++i) {
      const int c = i * 256 + tid;                   // 16B chunk id 0..511
      const int r = c >> 2;                          // tile row 0..127
      const int q = c & 3;                           // quarter within 64B row
      const int kb = (q ^ ((r >> 1) & 3)) * 16;      // pre-swizzled k-byte
      int gra = tileM + r; gra = gra < M ? gra : M - 1;
      const size_t aoff = (size_t)gra * (DIMD * 2) + (size_t)(k0 * 2 + kb);
      const size_t boff = (size_t)(tileN + r) * (DIMD * 2) + (size_t)(k0 * 2 + kb);
      const int lbase = c * 16;                      // linear LDS dest
      __builtin_amdgcn_global_load_lds((const __attribute__((address_space(1))) unsigned int*)((const char*)Ahi + aoff),
                                       (__attribute__((address_space(3))) unsigned int*)(sAhi + lbase), 16, 0, 0);
      __builtin_amdgcn_global_load_lds((const __attribute__((address_space(1))) unsigned int*)((const char*)Alo + aoff),
                                       (__attribute__((address_space(3))) unsigned int*)(sAlo + lbase), 16, 0, 0);
      __builtin_amdgcn_global_load_lds((const __attribute__((address_space(1))) unsigned int*)((const char*)BhiT + boff),
                                       (__attribute__((address_space(3))) unsigned int*)(sBhi + lbase), 16, 0, 0);
    }
    __syncthreads();
    const int qr = lane >> 4;                        // k-quarter this lane consumes
    short8 ah[4], al[4], bh[4];
    #pragma unroll
    for (int mf = 0; mf < 4; ++mf) {
      const int r = wm + mf * 16 + (lane & 15);
      const int kb = (qr ^ ((r >> 1) & 3)) * 16;
      ah[mf] = *(const short8*)(sAhi + r * 64 + kb);
      al[mf] = *(const short8*)(sAlo + r * 64 + kb);
    }
    #pragma unroll
    for (int nf = 0; nf < 4; ++nf) {
      const int r = wn + nf * 16 + (lane & 15);
      const int kb = (qr ^ ((r >> 1) & 3)) * 16;
      bh[nf] = *(const short8*)(sBhi + r * 64 + kb);
    }
    #pragma unroll
    for (int mf = 0; mf < 4; ++mf) {
      #pragma unroll
      for (int nf = 0; nf < 4; ++nf) {
        acc[mf][nf] = __builtin_amdgcn_mfma_f32_16x16x32_bf16(ah[mf], bh[nf], acc[mf][nf], 0, 0, 0);
        acc[mf][nf] = __builtin_amdgcn_mfma_f32_16x16x32_bf16(al[mf], bh[nf], acc[mf][nf], 0, 0, 0);
      }
    }
    __syncthreads();
  }
  #pragma unroll
  for (int mf = 0; mf < 4; ++mf) {
    const int rb = tileM + wm + mf * 16 + (lane >> 4) * 4;
    #pragma unroll
    for (int nf = 0; nf < 4; ++nf) {
      const int col = tileN + wn + nf * 16 + (lane & 15);
      #pragma unroll
      for (int j = 0; j < 4; ++j) {
        const int row = rb + j;
        if (row < M) C[(size_t)row * DIMD + col] = f2bf(acc[mf][nf][j]);
      }
    }
  }
}

// ---------------- fp32 tiled GEMM (fallback) ----------------

__global__ __launch_bounds__(256) void gemm_fp32(const float* __restrict__ A, const float* __restrict__ W,
                                                 float* __restrict__ C, int M) {
  const int K = DIMD, N = DIMD;
  __shared__ float As[16][65];
  __shared__ float Bs[16][64];
  int tid = threadIdx.x;
  int tileM = blockIdx.x * 64;
  int tileN = blockIdx.y * 64;
  int tx = tid & 15, ty = tid >> 4;
  float acc[4][4] = {};
  int arow = tid >> 2;
  int acol = (tid & 3) * 4;
  int brow = tid >> 4;
  int bcol = (tid & 15) * 4;

  for (int k0 = 0; k0 < K; k0 += 16) {
    float4 a4 = make_float4(0.f, 0.f, 0.f, 0.f);
    int gr = tileM + arow;
    if (gr < M) a4 = *(const float4*)(A + (size_t)gr * K + k0 + acol);
    As[acol + 0][arow] = a4.x;
    As[acol + 1][arow] = a4.y;
    As[acol + 2][arow] = a4.z;
    As[acol + 3][arow] = a4.w;
    float4 b4 = *(const float4*)(W + (size_t)(k0 + brow) * N + tileN + bcol);
    *(float4*)(&Bs[brow][bcol]) = b4;
    __syncthreads();
    #pragma unroll
    for (int kk = 0; kk < 16; ++kk) {
      float a[4];
      #pragma unroll
      for (int i = 0; i < 4; ++i) a[i] = As[kk][ty * 4 + i];
      float4 b = *(const float4*)(&Bs[kk][tx * 4]);
      #pragma unroll
      for (int i = 0; i < 4; ++i) {
        acc[i][0] += a[i] * b.x;
        acc[i][1] += a[i] * b.y;
        acc[i][2] += a[i] * b.z;
        acc[i][3] += a[i] * b.w;
      }
    }
    __syncthreads();
  }
  #pragma unroll
  for (int i = 0; i < 4; ++i) {
    int gr = tileM + ty * 4 + i;
    if (gr < M) {
      float4 o = make_float4(acc[i][0], acc[i][1], acc[i][2], acc[i][3]);
      *(float4*)(C + (size_t)gr * N + tileN + tx * 4) = o;
    }
  }
}

// ---------------- fused aggregation (bf16 gather), one WAVE per node ----------------
// mid layers: out = relu(agg*nd + b) -> LN(g,bb) -> *ns -> split to Ahi/Alo
// final layer: out = agg*nd + b -> fp32 d_out

template <int MODE>  // 0 = mid (fused relu+LN+ns+split), 1 = final
__global__ __launch_bounds__(256) void agg_fused(const unsigned short* __restrict__ Y,
                                                 const int* __restrict__ rp, const int* __restrict__ eidx,
                                                 const float* __restrict__ nd, const float* __restrict__ bias,
                                                 const float* __restrict__ g, const float* __restrict__ bb,
                                                 const float* __restrict__ ns,
                                                 unsigned short* __restrict__ Ahi, unsigned short* __restrict__ Alo,
                                                 float* __restrict__ outf, int n) {
  const int lane = threadIdx.x & 63;
  const int v = blockIdx.x * 4 + (threadIdx.x >> 6);
  if (v >= n) return;
  const int beg = rp[v], end = rp[v + 1];
  float acc[8] = {0.f, 0.f, 0.f, 0.f, 0.f, 0.f, 0.f, 0.f};
  int j = beg;
  for (; j + 3 < end; j += 4) {
    const short8 m0 = *(const short8*)(Y + (size_t)eidx[j] * DIMD + lane * 8);
    const short8 m1 = *(const short8*)(Y + (size_t)eidx[j + 1] * DIMD + lane * 8);
    const short8 m2 = *(const short8*)(Y + (size_t)eidx[j + 2] * DIMD + lane * 8);
    const short8 m3 = *(const short8*)(Y + (size_t)eidx[j + 3] * DIMD + lane * 8);
    #pragma unroll
    for (int k = 0; k < 8; ++k)
      acc[k] += (bf2f((unsigned short)m0[k]) + bf2f((unsigned short)m1[k])) +
                (bf2f((unsigned short)m2[k]) + bf2f((unsigned short)m3[k]));
  }
  for (; j < end; ++j) {
    const short8 m0 = *(const short8*)(Y + (size_t)eidx[j] * DIMD + lane * 8);
    #pragma unroll
    for (int k = 0; k < 8; ++k) acc[k] += bf2f((unsigned short)m0[k]);
  }
  const float f = nd[v];
  const float4 bA = ((const float4*)(bias))[lane * 2];
  const float4 bB = ((const float4*)(bias))[lane * 2 + 1];
  float o[8];
  o[0] = acc[0] * f + bA.x; o[1] = acc[1] * f + bA.y; o[2] = acc[2] * f + bA.z; o[3] = acc[3] * f + bA.w;
  o[4] = acc[4] * f + bB.x; o[5] = acc[5] * f + bB.y; o[6] = acc[6] * f + bB.z; o[7] = acc[7] * f + bB.w;
  if (MODE == 0) {
    #pragma unroll
    for (int k = 0; k < 8; ++k) o[k] = fmaxf(o[k], 0.f);
    float s = 0.f;
    #pragma unroll
    for (int k = 0; k < 8; ++k) s += o[k];
    #pragma unroll
    for (int m = 32; m; m >>= 1) s += __shfl_xor(s, m);
    const float mu = s * (1.0f / 512.0f);
    float s2 = 0.f;
    float c[8];
    #pragma unroll
    for (int k = 0; k < 8; ++k) { c[k] = o[k] - mu; s2 += c[k] * c[k]; }
    #pragma unroll
    for (int m = 32; m; m >>= 1) s2 += __shfl_xor(s2, m);
    const float rstd = rsqrtf(s2 * (1.0f / 512.0f) + LNEPS);
    const float scale = ns[v];
    const float4 gA = ((const float4*)(g))[lane * 2];
    const float4 gB = ((const float4*)(g))[lane * 2 + 1];
    const float4 lA = ((const float4*)(bb))[lane * 2];
    const float4 lB = ((const float4*)(bb))[lane * 2 + 1];
    float val[8];
    val[0] = (c[0] * rstd * gA.x + lA.x) * scale;
    val[1] = (c[1] * rstd * gA.y + lA.y) * scale;
    val[2] = (c[2] * rstd * gA.z + lA.z) * scale;
    val[3] = (c[3] * rstd * gA.w + lA.w) * scale;
    val[4] = (c[4] * rstd * gB.x + lB.x) * scale;
    val[5] = (c[5] * rstd * gB.y + lB.y) * scale;
    val[6] = (c[6] * rstd * gB.z + lB.z) * scale;
    val[7] = (c[7] * rstd * gB.w + lB.w) * scale;
    short8 hv, lv;
    #pragma unroll
    for (int k = 0; k < 8; ++k) {
      unsigned short hh = f2bf(val[k]);
      hv[k] = (short)hh;
      lv[k] = (short)f2bf(val[k] - bf2f(hh));
    }
    *(short8*)(Ahi + (size_t)v * DIMD + lane * 8) = hv;
    *(short8*)(Alo + (size_t)v * DIMD + lane * 8) = lv;
  } else {
    float4 oA = make_float4(o[0], o[1], o[2], o[3]);
    float4 oB = make_float4(o[4], o[5], o[6], o[7]);
    ((float4*)(outf + (size_t)v * DIMD + lane * 8))[0] = oA;
    ((float4*)(outf + (size_t)v * DIMD + lane * 8))[1] = oB;
  }
}

// ---------------- fp32 aggregation (fallback) ----------------

__global__ __launch_bounds__(128) void agg_kernel(const float* __restrict__ Y, const int* __restrict__ rp,
                                                  const int* __restrict__ eidx, const float* __restrict__ nd,
                                                  const float* __restrict__ bias, float* __restrict__ out,
                                                  int do_relu) {
  int v = blockIdx.x;
  int tid = threadIdx.x;
  int beg = rp[v], end = rp[v + 1];
  float4 acc = make_float4(0.f, 0.f, 0.f, 0.f);
  for (int j = beg; j < end; ++j) {
    int s = eidx[j];
    float4 m = ((const float4*)(Y + (size_t)s * DIMD))[tid];
    acc.x += m.x; acc.y += m.y; acc.z += m.z; acc.w += m.w;
  }
  float f = nd[v];
  float4 b4 = ((const float4*)bias)[tid];
  float4 o = make_float4(acc.x * f + b4.x, acc.y * f + b4.y, acc.z * f + b4.z, acc.w * f + b4.w);
  if (do_relu) {
    o.x = fmaxf(o.x, 0.f); o.y = fmaxf(o.y, 0.f); o.z = fmaxf(o.z, 0.f); o.w = fmaxf(o.w, 0.f);
  }
  ((float4*)(out + (size_t)v * DIMD))[tid] = o;
}

// ---------------- launch ----------------

extern "C" void kernel_launch(void* const* d_in, const int* in_sizes, int n_in,
                              void* d_out, int out_size, void* d_ws, size_t ws_size,
                              hipStream_t stream) {
  const float* feats = (const float*)d_in[0];
  const int* src = (const int*)d_in[1];
  const int* dst = (const int*)d_in[2];
  const float* ln_g = (const float*)d_in[3];
  const float* ln_b = (const float*)d_in[4];
  const float* W = (const float*)d_in[5];
  const float* bias = (const float*)d_in[6];
  const int n = in_sizes[0] / DIMD;
  const int e = in_sizes[1];
  const int L = in_sizes[3] / DIMD;  // 3

  char* ws = (char*)d_ws;
  size_t off = 0;
  auto alloc = [&](size_t bytes) {
    void* p = ws + off;
    off = (off + bytes + 255) & ~(size_t)255;
    return p;
  };

  const size_t misc_bytes = ((size_t)n * 4 + 256) * 6 + ((size_t)(n + 1) * 4 + 256) + ((size_t)e * 4 + 256);
  const size_t fast_need = 2 * ((size_t)(n + 128) * DIMD * 2 + 256)   // Ahi/Alo
                         + ((size_t)n * DIMD * 2 + 256)               // Ybf
                         + ((size_t)L * DIMD * DIMD * 2 + 256)        // WhiT
                         + misc_bytes;

  const bool fast = ws_size >= fast_need;

  float* O = (float*)d_out;
  int eb = (e + 255) / 256;
  int nb = (n + 255) / 256;

  if (fast) {
    unsigned short* Ahi = (unsigned short*)alloc((size_t)(n + 128) * DIMD * 2);
    unsigned short* Alo = (unsigned short*)alloc((size_t)(n + 128) * DIMD * 2);
    unsigned short* Ybf = (unsigned short*)alloc((size_t)n * DIMD * 2);
    unsigned short* WhiT = (unsigned short*)alloc((size_t)L * DIMD * DIMD * 2);
    float* ns = (float*)alloc((size_t)n * 4);
    float* nd = (float*)alloc((size_t)n * 4);
    int* outdeg = (int*)alloc((size_t)n * 4);
    int* indeg = (int*)alloc((size_t)n * 4);
    int* rp = (int*)alloc((size_t)(n + 1) * 4);
    int* cursor = (int*)alloc((size_t)n * 4);
    int* eidx = (int*)alloc((size_t)e * 4);

    hipMemsetAsync(outdeg, 0, (size_t)n * 4, stream);
    hipMemsetAsync(indeg, 0, (size_t)n * 4, stream);

    int wtot = L * DIMD * DIMD;
    wsplit_kernel<<<(wtot + 255) / 256, 256, 0, stream>>>(W, WhiT, wtot);
    deg_kernel<<<eb, 256, 0, stream>>>(src, dst, outdeg, indeg, e);
    norm_kernel<<<nb, 256, 0, stream>>>(outdeg, indeg, ns, nd, n);
    scan_kernel<<<1, 1024, 0, stream>>>(indeg, rp, cursor, n);
    fill_kernel<<<eb, 256, 0, stream>>>(src, dst, cursor, eidx, e);

    dim3 ggrid(DIMD / 128, (n + 127) / 128);  // N-tiles fastest: A-slice L2/L3 reuse
    int agrid = (n + 3) / 4;
    ln_split_kernel<<<n, 128, 0, stream>>>(feats, Ahi, Alo, ln_g, ln_b, ns);
    for (int l = 0; l < L; ++l) {
      gemm_mfma_bf16out<<<ggrid, 256, 0, stream>>>(Ahi, Alo, WhiT + (size_t)l * DIMD * DIMD, Ybf, n);
      if (l < L - 1) {
        agg_fused<0><<<agrid, 256, 0, stream>>>(Ybf, rp, eidx, nd, bias + (size_t)l * DIMD,
                                                ln_g + (size_t)(l + 1) * DIMD, ln_b + (size_t)(l + 1) * DIMD,
                                                ns, Ahi, Alo, nullptr, n);
      } else {
        agg_fused<1><<<agrid, 256, 0, stream>>>(Ybf, rp, eidx, nd, bias + (size_t)l * DIMD,
                                                nullptr, nullptr, nullptr, nullptr, nullptr, O, n);
      }
    }
  } else {
    // fallback: fp32 pipeline
    float* X = (float*)alloc((size_t)n * DIMD * 4);
    float* ns = (float*)alloc((size_t)n * 4);
    float* nd = (float*)alloc((size_t)n * 4);
    int* outdeg = (int*)alloc((size_t)n * 4);
    int* indeg = (int*)alloc((size_t)n * 4);
    int* rp = (int*)alloc((size_t)(n + 1) * 4);
    int* cursor = (int*)alloc((size_t)n * 4);
    int* eidx = (int*)alloc((size_t)e * 4);

    hipMemsetAsync(outdeg, 0, (size_t)n * 4, stream);
    hipMemsetAsync(indeg, 0, (size_t)n * 4, stream);

    deg_kernel<<<eb, 256, 0, stream>>>(src, dst, outdeg, indeg, e);
    norm_kernel<<<nb, 256, 0, stream>>>(outdeg, indeg, ns, nd, n);
    scan_kernel<<<1, 1024, 0, stream>>>(indeg, rp, cursor, n);
    fill_kernel<<<eb, 256, 0, stream>>>(src, dst, cursor, eidx, e);

    const float* cur = feats;
    dim3 ggrid((n + 63) / 64, DIMD / 64);
    for (int l = 0; l < L; ++l) {
      int s = 3 * l;
      float* ln_out = (s & 1) ? X : O;
      float* mm_out = ((s + 1) & 1) ? X : O;
      float* ag_out = ((s + 2) & 1) ? X : O;
      ln_scale_kernel<<<n, 128, 0, stream>>>(cur, ln_out, ln_g + (size_t)l * DIMD, ln_b + (size_t)l * DIMD, ns);
      gemm_fp32<<<ggrid, 256, 0, stream>>>(ln_out, W + (size_t)l * DIMD * DIMD, mm_out, n);
      agg_kernel<<<n, 128, 0, stream>>>(mm_out, rp, eidx, nd, bias + (size_t)l * DIMD, ag_out, (l < L - 1) ? 1 : 0);
      cur = ag_out;
    }
  }
}

// Round 9
// 295.982 us; speedup vs baseline: 1.3998x; 1.1994x over previous
//
#include <hip/hip_runtime.h>
#include <hip/hip_bf16.h>
#include <stdint.h>

#define DIMD 512
#define LNEPS 1e-5f

typedef __attribute__((ext_vector_type(8))) short short8;
typedef __attribute__((ext_vector_type(4))) float f32x4;

static __device__ __forceinline__ unsigned short f2bf(float x) {
  unsigned u = __builtin_bit_cast(unsigned, x);
  unsigned r = (u + 0x7FFFu + ((u >> 16) & 1u)) >> 16;
  return (unsigned short)r;
}
static __device__ __forceinline__ float bf2f(unsigned short h) {
  return __builtin_bit_cast(float, ((unsigned)h) << 16);
}

// ---------------- degree / CSR build ----------------

__global__ __launch_bounds__(256) void deg_kernel(const int* __restrict__ src, const int* __restrict__ dst,
                                                  int* __restrict__ outdeg, int* __restrict__ indeg, int e) {
  int i = blockIdx.x * 256 + threadIdx.x;
  if (i < e) {
    atomicAdd(&outdeg[src[i]], 1);
    atomicAdd(&indeg[dst[i]], 1);
  }
}

__global__ __launch_bounds__(256) void norm_kernel(const int* __restrict__ outdeg, const int* __restrict__ indeg,
                                                   float* __restrict__ ns, float* __restrict__ nd, int n) {
  int i = blockIdx.x * 256 + threadIdx.x;
  if (i < n) {
    ns[i] = rsqrtf((float)max(outdeg[i], 1));
    nd[i] = rsqrtf((float)max(indeg[i], 1));
  }
}

// wave-shfl based block scan, single block of 1024 threads
__global__ __launch_bounds__(1024) void scan_kernel(const int* __restrict__ cnt, int* __restrict__ rp,
                                                    int* __restrict__ cursor, int n) {
  __shared__ int wsum[16];
  __shared__ int carry_s;
  const int tid = threadIdx.x;
  const int lane = tid & 63;
  const int wid = tid >> 6;
  if (tid == 0) carry_s = 0;
  __syncthreads();
  for (int base = 0; base < n; base += 1024) {
    const int i = base + tid;
    const int x = (i < n) ? cnt[i] : 0;
    int incl = x;
    #pragma unroll
    for (int o = 1; o < 64; o <<= 1) {
      int t = __shfl_up(incl, o);
      if (lane >= o) incl += t;
    }
    if (lane == 63) wsum[wid] = incl;
    __syncthreads();
    if (wid == 0) {
      int v = (lane < 16) ? wsum[lane] : 0;
      #pragma unroll
      for (int o = 1; o < 16; o <<= 1) {
        int t = __shfl_up(v, o);
        if (lane >= o) v += t;
      }
      if (lane < 16) wsum[lane] = v;
    }
    __syncthreads();
    const int carry = carry_s;
    const int woff = wid ? wsum[wid - 1] : 0;
    if (i < n) {
      const int excl = carry + woff + incl - x;
      rp[i] = excl;
      cursor[i] = excl;
    }
    __syncthreads();
    if (tid == 0) carry_s = carry + wsum[15];
    __syncthreads();
  }
  if (tid == 0) rp[n] = carry_s;
}

__global__ __launch_bounds__(256) void fill_kernel(const int* __restrict__ src, const int* __restrict__ dst,
                                                   int* __restrict__ cursor, int* __restrict__ eidx, int e) {
  int i = blockIdx.x * 256 + threadIdx.x;
  if (i < e) {
    int p = atomicAdd(&cursor[dst[i]], 1);
    eidx[p] = src[i];
  }
}

// ---------------- W bf16 + transpose ----------------

__global__ __launch_bounds__(256) void wsplit_kernel(const float* __restrict__ W,
                                                     unsigned short* __restrict__ WhiT, int total) {
  int idx = blockIdx.x * 256 + threadIdx.x;
  if (idx >= total) return;
  int l = idx >> 18;
  int rem = idx & 262143;
  int k = rem >> 9;
  int nn = rem & 511;
  float w = W[idx];
  size_t o = ((size_t)l << 18) + ((size_t)nn << 9) + (size_t)k;
  WhiT[o] = f2bf(w);
}

// ---------------- layer-0 LayerNorm + ns scaling -> bf16 ----------------

__global__ __launch_bounds__(128) void ln_split_kernel(const float* __restrict__ h,
                                                       unsigned short* __restrict__ Abf,
                                                       const float* __restrict__ g, const float* __restrict__ bb,
                                                       const float* __restrict__ ns) {
  int v = blockIdx.x;
  int tid = threadIdx.x;
  const float4* hv = (const float4*)(h + (size_t)v * DIMD);
  float4 x = hv[tid];
  float s = x.x + x.y + x.z + x.w;
  #pragma unroll
  for (int m = 32; m; m >>= 1) s += __shfl_xor(s, m);
  __shared__ float red[2];
  __shared__ float red2[2];
  int wid = tid >> 6;
  if ((tid & 63) == 0) red[wid] = s;
  __syncthreads();
  float mu = (red[0] + red[1]) * (1.0f / 512.0f);
  float4 c = make_float4(x.x - mu, x.y - mu, x.z - mu, x.w - mu);
  float s2 = c.x * c.x + c.y * c.y + c.z * c.z + c.w * c.w;
  #pragma unroll
  for (int m = 32; m; m >>= 1) s2 += __shfl_xor(s2, m);
  if ((tid & 63) == 0) red2[wid] = s2;
  __syncthreads();
  float var = (red2[0] + red2[1]) * (1.0f / 512.0f);
  float rstd = rsqrtf(var + LNEPS);
  float scale = ns[v];
  float4 g4 = ((const float4*)g)[tid];
  float4 b4 = ((const float4*)bb)[tid];
  ushort4 h4;
  h4.x = f2bf((c.x * rstd * g4.x + b4.x) * scale);
  h4.y = f2bf((c.y * rstd * g4.y + b4.y) * scale);
  h4.z = f2bf((c.z * rstd * g4.z + b4.z) * scale);
  h4.w = f2bf((c.w * rstd * g4.w + b4.w) * scale);
  ((ushort4*)(Abf + (size_t)v * DIMD))[tid] = h4;
}

// ---------------- fp32 LN (fallback path) ----------------

__global__ __launch_bounds__(128) void ln_scale_kernel(const float* __restrict__ h, float* __restrict__ out,
                                                       const float* __restrict__ g, const float* __restrict__ bb,
                                                       const float* __restrict__ ns) {
  int v = blockIdx.x;
  int tid = threadIdx.x;
  const float4* hv = (const float4*)(h + (size_t)v * DIMD);
  float4 x = hv[tid];
  float s = x.x + x.y + x.z + x.w;
  #pragma unroll
  for (int m = 32; m; m >>= 1) s += __shfl_xor(s, m);
  __shared__ float red[2];
  __shared__ float red2[2];
  int wid = tid >> 6;
  if ((tid & 63) == 0) red[wid] = s;
  __syncthreads();
  float mu = (red[0] + red[1]) * (1.0f / 512.0f);
  float4 c = make_float4(x.x - mu, x.y - mu, x.z - mu, x.w - mu);
  float s2 = c.x * c.x + c.y * c.y + c.z * c.z + c.w * c.w;
  #pragma unroll
  for (int m = 32; m; m >>= 1) s2 += __shfl_xor(s2, m);
  if ((tid & 63) == 0) red2[wid] = s2;
  __syncthreads();
  float var = (red2[0] + red2[1]) * (1.0f / 512.0f);
  float rstd = rsqrtf(var + LNEPS);
  float scale = ns[v];
  float4 g4 = ((const float4*)g)[tid];
  float4 b4 = ((const float4*)bb)[tid];
  float4 o;
  o.x = (c.x * rstd * g4.x + b4.x) * scale;
  o.y = (c.y * rstd * g4.y + b4.y) * scale;
  o.z = (c.z * rstd * g4.z + b4.z) * scale;
  o.w = (c.w * rstd * g4.w + b4.w) * scale;
  ((float4*)(out + (size_t)v * DIMD))[tid] = o;
}

// ---------------- bf16 MFMA GEMM (single product), BK=32, 16KB LDS ----------------
// grid = (N/128, ceil(M/128)): N-tiles fastest so sibling blocks reuse the A-slice via L2/L3

__global__ __launch_bounds__(256, 4) void gemm_mfma_bf16out(const unsigned short* __restrict__ Abf,
                                                            const unsigned short* __restrict__ BhiT,
                                                            unsigned short* __restrict__ C, int M) {
  __shared__ char lds[16384];
  char* sA = lds;              // 128 rows x 64 B
  char* sB = lds + 8192;
  const int tid = threadIdx.x;
  const int lane = tid & 63;
  const int w = tid >> 6;
  const int tileM = blockIdx.y * 128;
  const int tileN = blockIdx.x * 128;
  const int wm = (w >> 1) * 64;
  const int wn = (w & 1) * 64;

  f32x4 acc[4][4] = {};

  for (int k0 = 0; k0 < DIMD; k0 += 32) {
    #pragma unroll
    for (int i = 0; i < 2; ++i) {
      const int c = i * 256 + tid;                   // 16B chunk id 0..511
      const int r = c >> 2;                          // tile row 0..127
      const int q = c & 3;                           // quarter within 64B row
      const int kb = (q ^ ((r >> 1) & 3)) * 16;      // pre-swizzled k-byte
      int gra = tileM + r; gra = gra < M ? gra : M - 1;
      const size_t aoff = (size_t)gra * (DIMD * 2) + (size_t)(k0 * 2 + kb);
      const size_t boff = (size_t)(tileN + r) * (DIMD * 2) + (size_t)(k0 * 2 + kb);
      const int lbase = c * 16;                      // linear LDS dest
      __builtin_amdgcn_global_load_lds((const __attribute__((address_space(1))) unsigned int*)((const char*)Abf + aoff),
                                       (__attribute__((address_space(3))) unsigned int*)(sA + lbase), 16, 0, 0);
      __builtin_amdgcn_global_load_lds((const __attribute__((address_space(1))) unsigned int*)((const char*)BhiT + boff),
                                       (__attribute__((address_space(3))) unsigned int*)(sB + lbase), 16, 0, 0);
    }
    __syncthreads();
    const int qr = lane >> 4;                        // k-quarter this lane consumes
    short8 ah[4], bh[4];
    #pragma unroll
    for (int mf = 0; mf < 4; ++mf) {
      const int r = wm + mf * 16 + (lane & 15);
      const int kb = (qr ^ ((r >> 1) & 3)) * 16;
      ah[mf] = *(const short8*)(sA + r * 64 + kb);
    }
    #pragma unroll
    for (int nf = 0; nf < 4; ++nf) {
      const int r = wn + nf * 16 + (lane & 15);
      const int kb = (qr ^ ((r >> 1) & 3)) * 16;
      bh[nf] = *(const short8*)(sB + r * 64 + kb);
    }
    #pragma unroll
    for (int mf = 0; mf < 4; ++mf) {
      #pragma unroll
      for (int nf = 0; nf < 4; ++nf) {
        acc[mf][nf] = __builtin_amdgcn_mfma_f32_16x16x32_bf16(ah[mf], bh[nf], acc[mf][nf], 0, 0, 0);
      }
    }
    __syncthreads();
  }
  #pragma unroll
  for (int mf = 0; mf < 4; ++mf) {
    const int rb = tileM + wm + mf * 16 + (lane >> 4) * 4;
    #pragma unroll
    for (int nf = 0; nf < 4; ++nf) {
      const int col = tileN + wn + nf * 16 + (lane & 15);
      #pragma unroll
      for (int j = 0; j < 4; ++j) {
        const int row = rb + j;
        if (row < M) C[(size_t)row * DIMD + col] = f2bf(acc[mf][nf][j]);
      }
    }
  }
}

// ---------------- fp32 tiled GEMM (fallback) ----------------

__global__ __launch_bounds__(256) void gemm_fp32(const float* __restrict__ A, const float* __restrict__ W,
                                                 float* __restrict__ C, int M) {
  const int K = DIMD, N = DIMD;
  __shared__ float As[16][65];
  __shared__ float Bs[16][64];
  int tid = threadIdx.x;
  int tileM = blockIdx.x * 64;
  int tileN = blockIdx.y * 64;
  int tx = tid & 15, ty = tid >> 4;
  float acc[4][4] = {};
  int arow = tid >> 2;
  int acol = (tid & 3) * 4;
  int brow = tid >> 4;
  int bcol = (tid & 15) * 4;

  for (int k0 = 0; k0 < K; k0 += 16) {
    float4 a4 = make_float4(0.f, 0.f, 0.f, 0.f);
    int gr = tileM + arow;
    if (gr < M) a4 = *(const float4*)(A + (size_t)gr * K + k0 + acol);
    As[acol + 0][arow] = a4.x;
    As[acol + 1][arow] = a4.y;
    As[acol + 2][arow] = a4.z;
    As[acol + 3][arow] = a4.w;
    float4 b4 = *(const float4*)(W + (size_t)(k0 + brow) * N + tileN + bcol);
    *(float4*)(&Bs[brow][bcol]) = b4;
    __syncthreads();
    #pragma unroll
    for (int kk = 0; kk < 16; ++kk) {
      float a[4];
      #pragma unroll
      for (int i = 0; i < 4; ++i) a[i] = As[kk][ty * 4 + i];
      float4 b = *(const float4*)(&Bs[kk][tx * 4]);
      #pragma unroll
      for (int i = 0; i < 4; ++i) {
        acc[i][0] += a[i] * b.x;
        acc[i][1] += a[i] * b.y;
        acc[i][2] += a[i] * b.z;
        acc[i][3] += a[i] * b.w;
      }
    }
    __syncthreads();
  }
  #pragma unroll
  for (int i = 0; i < 4; ++i) {
    int gr = tileM + ty * 4 + i;
    if (gr < M) {
      float4 o = make_float4(acc[i][0], acc[i][1], acc[i][2], acc[i][3]);
      *(float4*)(C + (size_t)gr * N + tileN + tx * 4) = o;
    }
  }
}

// ---------------- fused aggregation (bf16 gather), one WAVE per node, 8-deep MLP ----------------
// mid layers: out = relu(agg*nd + b) -> LN(g,bb) -> *ns -> bf16 Abf
// final layer: out = agg*nd + b -> fp32 d_out

template <int MODE>  // 0 = mid (fused relu+LN+ns), 1 = final
__global__ __launch_bounds__(256) void agg_fused(const unsigned short* __restrict__ Y,
                                                 const int* __restrict__ rp, const int* __restrict__ eidx,
                                                 const float* __restrict__ nd, const float* __restrict__ bias,
                                                 const float* __restrict__ g, const float* __restrict__ bb,
                                                 const float* __restrict__ ns,
                                                 unsigned short* __restrict__ Abf,
                                                 float* __restrict__ outf, int n) {
  const int lane = threadIdx.x & 63;
  const int v = blockIdx.x * 4 + (threadIdx.x >> 6);
  if (v >= n) return;
  const int beg = rp[v], end = rp[v + 1];
  float acc[8] = {0.f, 0.f, 0.f, 0.f, 0.f, 0.f, 0.f, 0.f};
  int j = beg;
  for (; j + 7 < end; j += 8) {
    const short8 m0 = *(const short8*)(Y + (size_t)eidx[j] * DIMD + lane * 8);
    const short8 m1 = *(const short8*)(Y + (size_t)eidx[j + 1] * DIMD + lane * 8);
    const short8 m2 = *(const short8*)(Y + (size_t)eidx[j + 2] * DIMD + lane * 8);
    const short8 m3 = *(const short8*)(Y + (size_t)eidx[j + 3] * DIMD + lane * 8);
    const short8 m4 = *(const short8*)(Y + (size_t)eidx[j + 4] * DIMD + lane * 8);
    const short8 m5 = *(const short8*)(Y + (size_t)eidx[j + 5] * DIMD + lane * 8);
    const short8 m6 = *(const short8*)(Y + (size_t)eidx[j + 6] * DIMD + lane * 8);
    const short8 m7 = *(const short8*)(Y + (size_t)eidx[j + 7] * DIMD + lane * 8);
    #pragma unroll
    for (int k = 0; k < 8; ++k)
      acc[k] += ((bf2f((unsigned short)m0[k]) + bf2f((unsigned short)m1[k])) +
                 (bf2f((unsigned short)m2[k]) + bf2f((unsigned short)m3[k]))) +
                ((bf2f((unsigned short)m4[k]) + bf2f((unsigned short)m5[k])) +
                 (bf2f((unsigned short)m6[k]) + bf2f((unsigned short)m7[k])));
  }
  for (; j + 3 < end; j += 4) {
    const short8 m0 = *(const short8*)(Y + (size_t)eidx[j] * DIMD + lane * 8);
    const short8 m1 = *(const short8*)(Y + (size_t)eidx[j + 1] * DIMD + lane * 8);
    const short8 m2 = *(const short8*)(Y + (size_t)eidx[j + 2] * DIMD + lane * 8);
    const short8 m3 = *(const short8*)(Y + (size_t)eidx[j + 3] * DIMD + lane * 8);
    #pragma unroll
    for (int k = 0; k < 8; ++k)
      acc[k] += (bf2f((unsigned short)m0[k]) + bf2f((unsigned short)m1[k])) +
                (bf2f((unsigned short)m2[k]) + bf2f((unsigned short)m3[k]));
  }
  for (; j < end; ++j) {
    const short8 m0 = *(const short8*)(Y + (size_t)eidx[j] * DIMD + lane * 8);
    #pragma unroll
    for (int k = 0; k < 8; ++k) acc[k] += bf2f((unsigned short)m0[k]);
  }
  const float f = nd[v];
  const float4 bA = ((const float4*)(bias))[lane * 2];
  const float4 bB = ((const float4*)(bias))[lane * 2 + 1];
  float o[8];
  o[0] = acc[0] * f + bA.x; o[1] = acc[1] * f + bA.y; o[2] = acc[2] * f + bA.z; o[3] = acc[3] * f + bA.w;
  o[4] = acc[4] * f + bB.x; o[5] = acc[5] * f + bB.y; o[6] = acc[6] * f + bB.z; o[7] = acc[7] * f + bB.w;
  if (MODE == 0) {
    #pragma unroll
    for (int k = 0; k < 8; ++k) o[k] = fmaxf(o[k], 0.f);
    float s = 0.f;
    #pragma unroll
    for (int k = 0; k < 8; ++k) s += o[k];
    #pragma unroll
    for (int m = 32; m; m >>= 1) s += __shfl_xor(s, m);
    const float mu = s * (1.0f / 512.0f);
    float s2 = 0.f;
    float c[8];
    #pragma unroll
    for (int k = 0; k < 8; ++k) { c[k] = o[k] - mu; s2 += c[k] * c[k]; }
    #pragma unroll
    for (int m = 32; m; m >>= 1) s2 += __shfl_xor(s2, m);
    const float rstd = rsqrtf(s2 * (1.0f / 512.0f) + LNEPS);
    const float scale = ns[v];
    const float4 gA = ((const float4*)(g))[lane * 2];
    const float4 gB = ((const float4*)(g))[lane * 2 + 1];
    const float4 lA = ((const float4*)(bb))[lane * 2];
    const float4 lB = ((const float4*)(bb))[lane * 2 + 1];
    short8 hv;
    hv[0] = (short)f2bf((c[0] * rstd * gA.x + lA.x) * scale);
    hv[1] = (short)f2bf((c[1] * rstd * gA.y + lA.y) * scale);
    hv[2] = (short)f2bf((c[2] * rstd * gA.z + lA.z) * scale);
    hv[3] = (short)f2bf((c[3] * rstd * gA.w + lA.w) * scale);
    hv[4] = (short)f2bf((c[4] * rstd * gB.x + lB.x) * scale);
    hv[5] = (short)f2bf((c[5] * rstd * gB.y + lB.y) * scale);
    hv[6] = (short)f2bf((c[6] * rstd * gB.z + lB.z) * scale);
    hv[7] = (short)f2bf((c[7] * rstd * gB.w + lB.w) * scale);
    *(short8*)(Abf + (size_t)v * DIMD + lane * 8) = hv;
  } else {
    float4 oA = make_float4(o[0], o[1], o[2], o[3]);
    float4 oB = make_float4(o[4], o[5], o[6], o[7]);
    ((float4*)(outf + (size_t)v * DIMD + lane * 8))[0] = oA;
    ((float4*)(outf + (size_t)v * DIMD + lane * 8))[1] = oB;
  }
}

// ---------------- fp32 aggregation (fallback) ----------------

__global__ __launch_bounds__(128) void agg_kernel(const float* __restrict__ Y, const int* __restrict__ rp,
                                                  const int* __restrict__ eidx, const float* __restrict__ nd,
                                                  const float* __restrict__ bias, float* __restrict__ out,
                                                  int do_relu) {
  int v = blockIdx.x;
  int tid = threadIdx.x;
  int beg = rp[v], end = rp[v + 1];
  float4 acc = make_float4(0.f, 0.f, 0.f, 0.f);
  for (int j = beg; j < end; ++j) {
    int s = eidx[j];
    float4 m = ((const float4*)(Y + (size_t)s * DIMD))[tid];
    acc.x += m.x; acc.y += m.y; acc.z += m.z; acc.w += m.w;
  }
  float f = nd[v];
  float4 b4 = ((const float4*)bias)[tid];
  float4 o = make_float4(acc.x * f + b4.x, acc.y * f + b4.y, acc.z * f + b4.z, acc.w * f + b4.w);
  if (do_relu) {
    o.x = fmaxf(o.x, 0.f); o.y = fmaxf(o.y, 0.f); o.z = fmaxf(o.z, 0.f); o.w = fmaxf(o.w, 0.f);
  }
  ((float4*)(out + (size_t)v * DIMD))[tid] = o;
}

// ---------------- launch ----------------

extern "C" void kernel_launch(void* const* d_in, const int* in_sizes, int n_in,
                              void* d_out, int out_size, void* d_ws, size_t ws_size,
                              hipStream_t stream) {
  const float* feats = (const float*)d_in[0];
  const int* src = (const int*)d_in[1];
  const int* dst = (const int*)d_in[2];
  const float* ln_g = (const float*)d_in[3];
  const float* ln_b = (const float*)d_in[4];
  const float* W = (const float*)d_in[5];
  const float* bias = (const float*)d_in[6];
  const int n = in_sizes[0] / DIMD;
  const int e = in_sizes[1];
  const int L = in_sizes[3] / DIMD;  // 3

  char* ws = (char*)d_ws;
  size_t off = 0;
  auto alloc = [&](size_t bytes) {
    void* p = ws + off;
    off = (off + bytes + 255) & ~(size_t)255;
    return p;
  };

  const size_t misc_bytes = ((size_t)n * 4 + 256) * 6 + ((size_t)(n + 1) * 4 + 256) + ((size_t)e * 4 + 256);
  const size_t fast_need = ((size_t)(n + 128) * DIMD * 2 + 256)      // Abf
                         + ((size_t)n * DIMD * 2 + 256)              // Ybf
                         + ((size_t)L * DIMD * DIMD * 2 + 256)       // WhiT
                         + misc_bytes;

  const bool fast = ws_size >= fast_need;

  float* O = (float*)d_out;
  int eb = (e + 255) / 256;
  int nb = (n + 255) / 256;

  if (fast) {
    unsigned short* Abf = (unsigned short*)alloc((size_t)(n + 128) * DIMD * 2);
    unsigned short* Ybf = (unsigned short*)alloc((size_t)n * DIMD * 2);
    unsigned short* WhiT = (unsigned short*)alloc((size_t)L * DIMD * DIMD * 2);
    float* ns = (float*)alloc((size_t)n * 4);
    float* nd = (float*)alloc((size_t)n * 4);
    int* outdeg = (int*)alloc((size_t)n * 4);
    int* indeg = (int*)alloc((size_t)n * 4);
    int* rp = (int*)alloc((size_t)(n + 1) * 4);
    int* cursor = (int*)alloc((size_t)n * 4);
    int* eidx = (int*)alloc((size_t)e * 4);

    hipMemsetAsync(outdeg, 0, (size_t)n * 4, stream);
    hipMemsetAsync(indeg, 0, (size_t)n * 4, stream);

    int wtot = L * DIMD * DIMD;
    wsplit_kernel<<<(wtot + 255) / 256, 256, 0, stream>>>(W, WhiT, wtot);
    deg_kernel<<<eb, 256, 0, stream>>>(src, dst, outdeg, indeg, e);
    norm_kernel<<<nb, 256, 0, stream>>>(outdeg, indeg, ns, nd, n);
    scan_kernel<<<1, 1024, 0, stream>>>(indeg, rp, cursor, n);
    fill_kernel<<<eb, 256, 0, stream>>>(src, dst, cursor, eidx, e);

    dim3 ggrid(DIMD / 128, (n + 127) / 128);  // N-tiles fastest: A-slice L2/L3 reuse
    int agrid = (n + 3) / 4;
    ln_split_kernel<<<n, 128, 0, stream>>>(feats, Abf, ln_g, ln_b, ns);
    for (int l = 0; l < L; ++l) {
      gemm_mfma_bf16out<<<ggrid, 256, 0, stream>>>(Abf, WhiT + (size_t)l * DIMD * DIMD, Ybf, n);
      if (l < L - 1) {
        agg_fused<0><<<agrid, 256, 0, stream>>>(Ybf, rp, eidx, nd, bias + (size_t)l * DIMD,
                                                ln_g + (size_t)(l + 1) * DIMD, ln_b + (size_t)(l + 1) * DIMD,
                                                ns, Abf, nullptr, n);
      } else {
        agg_fused<1><<<agrid, 256, 0, stream>>>(Ybf, rp, eidx, nd, bias + (size_t)l * DIMD,
                                                nullptr, nullptr, nullptr, nullptr, O, n);
      }
    }
  } else {
    // fallback: fp32 pipeline
    float* X = (float*)alloc((size_t)n * DIMD * 4);
    float* ns = (float*)alloc((size_t)n * 4);
    float* nd = (float*)alloc((size_t)n * 4);
    int* outdeg = (int*)alloc((size_t)n * 4);
    int* indeg = (int*)alloc((size_t)n * 4);
    int* rp = (int*)alloc((size_t)(n + 1) * 4);
    int* cursor = (int*)alloc((size_t)n * 4);
    int* eidx = (int*)alloc((size_t)e * 4);

    hipMemsetAsync(outdeg, 0, (size_t)n * 4, stream);
    hipMemsetAsync(indeg, 0, (size_t)n * 4, stream);

    deg_kernel<<<eb, 256, 0, stream>>>(src, dst, outdeg, indeg, e);
    norm_kernel<<<nb, 256, 0, stream>>>(outdeg, indeg, ns, nd, n);
    scan_kernel<<<1, 1024, 0, stream>>>(indeg, rp, cursor, n);
    fill_kernel<<<eb, 256, 0, stream>>>(src, dst, cursor, eidx, e);

    const float* cur = feats;
    dim3 ggrid((n + 63) / 64, DIMD / 64);
    for (int l = 0; l < L; ++l) {
      int s = 3 * l;
      float* ln_out = (s & 1) ? X : O;
      float* mm_out = ((s + 1) & 1) ? X : O;
      float* ag_out = ((s + 2) & 1) ? X : O;
      ln_scale_kernel<<<n, 128, 0, stream>>>(cur, ln_out, ln_g + (size_t)l * DIMD, ln_b + (size_t)l * DIMD, ns);
      gemm_fp32<<<ggrid, 256, 0, stream>>>(ln_out, W + (size_t)l * DIMD * DIMD, mm_out, n);
      agg_kernel<<<n, 128, 0, stream>>>(mm_out, rp, eidx, nd, bias + (size_t)l * DIMD, ag_out, (l < L - 1) ? 1 : 0);
      cur = ag_out;
    }
  }
}